// Round 1
// baseline (777.779 us; speedup 1.0000x reference)
//
#include <hip/hip_runtime.h>
#include <hip/hip_bf16.h>

// hierarch_sep_loss: preds [2, N, 100] fp32 probs, labs [2, N] int, cen [2, N] int
// out[0] = sum over mods of:
//   (n_u/N) * (-sum_{cen==0} log(p[i,lab_i]+EPS) / max(1,n_u))
// + (n_c/N) * (-sum_{cen==1} log(sum_{j>lab0_i} p[i,j]+EPS) / max(1,n_c)) * 0.5
// Memory-bound: 400 MB preds read once. One wave per row, shuffle reductions.

#define HSL_EPS 1e-10f

__global__ __launch_bounds__(256) void hsl_main(
    const float* __restrict__ preds,
    const int*   __restrict__ labs,
    const int*   __restrict__ cen,
    double*       __restrict__ sums,   // [4]: usum0, csum0, usum1, csum1
    unsigned int* __restrict__ cnts,   // [4]: ucnt0, ccnt0, ucnt1, ccnt1
    int N)
{
    const int lane   = threadIdx.x & 63;
    const int waveInBlk = threadIdx.x >> 6;                 // 0..3
    const long long wave   = ((long long)blockIdx.x * blockDim.x + threadIdx.x) >> 6;
    const long long nwaves = ((long long)gridDim.x * blockDim.x) >> 6;
    const long long R = 2LL * N;

    double usum[2] = {0.0, 0.0};
    double csum[2] = {0.0, 0.0};
    unsigned int ucnt[2] = {0u, 0u};
    unsigned int ccnt[2] = {0u, 0u};

    for (long long r = wave; r < R; r += nwaves) {
        const int m = (r >= N) ? 1 : 0;
        const long long i = r - (long long)m * N;           // row index within mod
        const float* row = preds + r * 100;

        // 100 floats per row: lanes 0..63 take j=lane, lanes 0..35 also j=64+lane
        float p0 = row[lane];
        float p1 = (lane < 36) ? row[64 + lane] : 0.0f;

        const int lab  = labs[r];      // this mod's label (gather index)
        const int lab0 = labs[i];      // mod-0 label drives censored suffix sum
        const int c    = cen[r];
        const int t1   = lab0 + 1;     // sum over j >= t1

        float sp = ((lane      >= t1) ? p0 : 0.0f)
                 + ((lane + 64 >= t1) ? p1 : 0.0f);         // p1 already 0 for lane>=36
        float gp = ((lane      == lab) ? p0 : 0.0f)
                 + ((lane + 64 == lab) ? p1 : 0.0f);

        #pragma unroll
        for (int off = 32; off > 0; off >>= 1) {
            sp += __shfl_down(sp, off, 64);
            gp += __shfl_down(gp, off, 64);
        }

        if (lane == 0) {
            if (c == 0) { usum[m] += (double)logf(gp + HSL_EPS); ucnt[m]++; }
            else        { csum[m] += (double)logf(sp + HSL_EPS); ccnt[m]++; }
        }
    }

    // Block-level reduction: 4 waves -> one set of atomics per block.
    __shared__ double sh_sums[4][4];          // [wave][slot]
    __shared__ unsigned int sh_cnts[4][4];
    if (lane == 0) {
        sh_sums[waveInBlk][0] = usum[0]; sh_sums[waveInBlk][1] = csum[0];
        sh_sums[waveInBlk][2] = usum[1]; sh_sums[waveInBlk][3] = csum[1];
        sh_cnts[waveInBlk][0] = ucnt[0]; sh_cnts[waveInBlk][1] = ccnt[0];
        sh_cnts[waveInBlk][2] = ucnt[1]; sh_cnts[waveInBlk][3] = ccnt[1];
    }
    __syncthreads();
    if (threadIdx.x == 0) {
        const int nw = blockDim.x >> 6;
        for (int slot = 0; slot < 4; ++slot) {
            double s = 0.0; unsigned int k = 0u;
            for (int w = 0; w < nw; ++w) { s += sh_sums[w][slot]; k += sh_cnts[w][slot]; }
            atomicAdd(&sums[slot], s);
            if (k) atomicAdd(&cnts[slot], k);
        }
    }
}

__global__ void hsl_final(const double* __restrict__ sums,
                          const unsigned int* __restrict__ cnts,
                          float* __restrict__ out, int N)
{
    if (threadIdx.x == 0 && blockIdx.x == 0) {
        float total = 0.0f;
        const float n = (float)N;
        for (int m = 0; m < 2; ++m) {
            const float nu = (float)cnts[2 * m + 0];
            const float nc = (float)cnts[2 * m + 1];
            const float us = (float)sums[2 * m + 0];   // sum log(g+eps) over uncensored
            const float cs = (float)sums[2 * m + 1];   // sum log(s+eps) over censored
            const float uncen_loss = -us / fmaxf(1.0f, nu);
            const float cen_loss   = -cs / fmaxf(1.0f, nc);
            total += (nu / n) * uncen_loss + (nc / n) * cen_loss * 0.5f;
        }
        out[0] = total;
    }
}

extern "C" void kernel_launch(void* const* d_in, const int* in_sizes, int n_in,
                              void* d_out, int out_size, void* d_ws, size_t ws_size,
                              hipStream_t stream)
{
    const float* preds = (const float*)d_in[0];
    const int*   labs  = (const int*)d_in[1];
    const int*   cen   = (const int*)d_in[2];
    float* out = (float*)d_out;

    const int twoN = in_sizes[1];          // labs flat size = 2*N
    const int N    = twoN / 2;             // B = in_sizes[0]/twoN == 100 (hardcoded in kernel)

    double*       sums = (double*)d_ws;                   // 4 doubles (32 B)
    unsigned int* cnts = (unsigned int*)((char*)d_ws + 32); // 4 uints (16 B)

    // ws is poisoned to 0xAA each call — zero the accumulators (capture-safe).
    hipMemsetAsync(d_ws, 0, 48, stream);

    const int threads = 256;
    const int blocks  = 2048;              // 8 blocks/CU, 32 waves/CU
    hsl_main<<<blocks, threads, 0, stream>>>(preds, labs, cen, sums, cnts, N);
    hsl_final<<<1, 64, 0, stream>>>(sums, cnts, out, N);
}

// Round 2
// 650.867 us; speedup vs baseline: 1.1950x; 1.1950x over previous
//
#include <hip/hip_runtime.h>
#include <hip/hip_bf16.h>

// hierarch_sep_loss: preds [2, N, 100] fp32 probs, labs [2, N] int, cen [2, N] int
// out[0] = sum over mods of:
//   (n_u/N) * (-sum_{cen==0} log(p[i,lab_i]+EPS) / max(1,n_u))
// + (n_c/N) * (-sum_{cen==1} log(sum_{j>lab0_i} p[i,j]+EPS) / max(1,n_c)) * 0.5
//
// R1 analysis: one-wave-per-row + 12-shuffle reduction chain was latency-bound
// (641 GB/s). R2: LDS-staged tiles, quarter-row-per-thread with interleaved
// element mapping j = q + 4k (bank = (t+4k)%32 -> 2 lanes/bank = conflict-free),
// only 2 shfl_xor steps per row-group.

#define HSL_EPS 1e-10f
#define TILE_ROWS 64
#define TILE_FLOATS (TILE_ROWS * 100)   // 6400 floats = 25.6 KB LDS

__global__ __launch_bounds__(256) void hsl_main(
    const float* __restrict__ preds,
    const int*   __restrict__ labs,
    const int*   __restrict__ cen,
    double*       __restrict__ sums,   // [4]: usum0, csum0, usum1, csum1
    unsigned int* __restrict__ cnts,   // [4]: ucnt0, ccnt0, ucnt1, ccnt1
    long long N)
{
    __shared__ float tile[TILE_FLOATS];

    const int tid  = threadIdx.x;
    const int row  = tid >> 2;          // 0..63 within tile
    const int q    = tid & 3;           // quarter: elements j = q + 4k, k=0..24
    const long long R = 2LL * N;
    const long long ntiles = (R + TILE_ROWS - 1) / TILE_ROWS;

    double usum[2] = {0.0, 0.0};
    double csum[2] = {0.0, 0.0};
    unsigned int ucnt[2] = {0u, 0u};
    unsigned int ccnt[2] = {0u, 0u};

    for (long long tb = blockIdx.x; tb < ntiles; tb += gridDim.x) {
        const long long r0 = tb * TILE_ROWS;

        __syncthreads();   // previous iteration's scan must finish before restage

        // ---- stage 64 rows (6400 floats) coalesced: float4 global -> LDS ----
        const long long availF = (R - r0) * 100;              // floats available
        const float4* src = (const float4*)(preds + r0 * 100); // 16B aligned (25600B tiles)
        float4* dst = (float4*)tile;
        if (availF >= TILE_FLOATS) {
            #pragma unroll
            for (int k = 0; k < 7; ++k) {
                int i = tid + 256 * k;
                if (i < TILE_FLOATS / 4) dst[i] = src[i];
            }
        } else {
            for (int i = tid; i < TILE_FLOATS / 4; i += 256) {
                float4 v = make_float4(0.f, 0.f, 0.f, 0.f);
                if ((long long)i * 4 + 3 < availF) v = src[i];
                dst[i] = v;
            }
        }
        __syncthreads();

        // ---- scan: thread owns quarter-row, interleaved elements ----
        const long long r = r0 + row;
        float sp = 0.0f, gp = 0.0f;
        int m = 0, c = 0;
        bool valid = (r < R);
        if (valid) {
            m = (r >= N) ? 1 : 0;
            const long long i0 = r - (long long)m * N;
            const int lab = labs[r];
            const int t1  = labs[i0] + 1;
            c = cen[r];

            const float* prow = tile + row * 100;
            #pragma unroll
            for (int k = 0; k < 25; ++k) {
                const int j = q + 4 * k;
                const float p = prow[j];
                sp += (j >= t1) ? p : 0.0f;
                gp  = (j == lab) ? p : gp;
            }
        }
        // combine 4 quarter-partials (lanes 4r..4r+3 adjacent in the wave)
        sp += __shfl_xor(sp, 1, 64); sp += __shfl_xor(sp, 2, 64);
        gp += __shfl_xor(gp, 1, 64); gp += __shfl_xor(gp, 2, 64);

        if (valid && q == 0) {
            if (c == 0) { usum[m] += (double)logf(gp + HSL_EPS); ucnt[m]++; }
            else        { csum[m] += (double)logf(sp + HSL_EPS); ccnt[m]++; }
        }
    }

    // ---- wave-level shuffle reduction, then block-level LDS, then atomics ----
    #pragma unroll
    for (int off = 32; off > 0; off >>= 1) {
        usum[0] += __shfl_down(usum[0], off, 64);
        csum[0] += __shfl_down(csum[0], off, 64);
        usum[1] += __shfl_down(usum[1], off, 64);
        csum[1] += __shfl_down(csum[1], off, 64);
        ucnt[0] += __shfl_down(ucnt[0], off, 64);
        ccnt[0] += __shfl_down(ccnt[0], off, 64);
        ucnt[1] += __shfl_down(ucnt[1], off, 64);
        ccnt[1] += __shfl_down(ccnt[1], off, 64);
    }

    __shared__ double sh_sums[4][4];
    __shared__ unsigned int sh_cnts[4][4];
    const int waveInBlk = tid >> 6;
    const int lane = tid & 63;
    if (lane == 0) {
        sh_sums[waveInBlk][0] = usum[0]; sh_sums[waveInBlk][1] = csum[0];
        sh_sums[waveInBlk][2] = usum[1]; sh_sums[waveInBlk][3] = csum[1];
        sh_cnts[waveInBlk][0] = ucnt[0]; sh_cnts[waveInBlk][1] = ccnt[0];
        sh_cnts[waveInBlk][2] = ucnt[1]; sh_cnts[waveInBlk][3] = ccnt[1];
    }
    __syncthreads();
    if (tid == 0) {
        for (int slot = 0; slot < 4; ++slot) {
            double s = 0.0; unsigned int k = 0u;
            for (int w = 0; w < 4; ++w) { s += sh_sums[w][slot]; k += sh_cnts[w][slot]; }
            atomicAdd(&sums[slot], s);
            if (k) atomicAdd(&cnts[slot], k);
        }
    }
}

__global__ void hsl_final(const double* __restrict__ sums,
                          const unsigned int* __restrict__ cnts,
                          float* __restrict__ out, long long N)
{
    if (threadIdx.x == 0 && blockIdx.x == 0) {
        float total = 0.0f;
        const float n = (float)N;
        for (int m = 0; m < 2; ++m) {
            const float nu = (float)cnts[2 * m + 0];
            const float nc = (float)cnts[2 * m + 1];
            const float us = (float)sums[2 * m + 0];
            const float cs = (float)sums[2 * m + 1];
            const float uncen_loss = -us / fmaxf(1.0f, nu);
            const float cen_loss   = -cs / fmaxf(1.0f, nc);
            total += (nu / n) * uncen_loss + (nc / n) * cen_loss * 0.5f;
        }
        out[0] = total;
    }
}

extern "C" void kernel_launch(void* const* d_in, const int* in_sizes, int n_in,
                              void* d_out, int out_size, void* d_ws, size_t ws_size,
                              hipStream_t stream)
{
    const float* preds = (const float*)d_in[0];
    const int*   labs  = (const int*)d_in[1];
    const int*   cen   = (const int*)d_in[2];
    float* out = (float*)d_out;

    const long long N = (long long)(in_sizes[1] / 2);   // labs flat = 2*N; B=100 hardcoded

    double*       sums = (double*)d_ws;
    unsigned int* cnts = (unsigned int*)((char*)d_ws + 32);

    hipMemsetAsync(d_ws, 0, 48, stream);

    // LDS 25.6 KB/block -> 6 blocks/CU resident; 1536 = 6 * 256 CUs
    const int threads = 256;
    const int blocks  = 1536;
    hsl_main<<<blocks, threads, 0, stream>>>(preds, labs, cen, sums, cnts, N);
    hsl_final<<<1, 64, 0, stream>>>(sums, cnts, out, N);
}